// Round 6
// baseline (678.408 us; speedup 1.0000x reference)
//
#include <hip/hip_runtime.h>
#include <hip/hip_bf16.h>

// TriangleMultiplication on MI355X (gfx950).
// Pipeline: k_prep ; k_proj<0> (leftT) ; k_proj<1> (rightTT) ; k_tri (tri[h][pos]) ;
//           k_trT (tri -> triT[pos][h]) ; k_final v6 (C^T form: weights-in-registers).
// ws layout: WlT|WrT|WgT|WoT (4*32KB) + leftT/triT (64MB) + rightTT (64MB) + tri (64MB)

#define LSZ 512
#define NPOS (LSZ * LSZ)  // 262144 positions

typedef short s16;
typedef __attribute__((ext_vector_type(4))) short s16x4;
typedef __attribute__((ext_vector_type(8))) short s16x8;
typedef __attribute__((ext_vector_type(4))) float f32x4;

typedef const __attribute__((address_space(1))) unsigned int* gas1;
typedef __attribute__((address_space(3))) unsigned int* las3;

static __device__ __forceinline__ s16 f2bf(float f) {
    unsigned int u = __builtin_bit_cast(unsigned int, f);
    u += 0x7FFFu + ((u >> 16) & 1u);
    return (s16)(u >> 16);
}

static __device__ __forceinline__ void gload_lds16(const void* g, void* l) {
    __builtin_amdgcn_global_load_lds((gas1)g, (las3)l, 16, 0, 0);
}

// ---------------- K0: transpose weights to bf16 [out][in] ----------------
__global__ void k_prep(const float* __restrict__ Wl, const float* __restrict__ Wr,
                       const float* __restrict__ Wg, const float* __restrict__ Wo,
                       s16* __restrict__ WlT, s16* __restrict__ WrT,
                       s16* __restrict__ WgT, s16* __restrict__ WoT) {
    const float* src;
    s16* dst;
    switch (blockIdx.x) {
        case 0: src = Wl; dst = WlT; break;
        case 1: src = Wr; dst = WrT; break;
        case 2: src = Wg; dst = WgT; break;
        default: src = Wo; dst = WoT; break;
    }
    for (int e = threadIdx.x; e < 128 * 128; e += blockDim.x) {
        int o = e >> 7, i = e & 127;
        dst[e] = f2bf(src[i * 128 + o]);  // WT[o][i] = W[i][o]
    }
}

// ---------------- K1: projection GEMM, output transposed [h][pos] ----------------
template <int COLMODE>
__global__ __launch_bounds__(256) void k_proj(const float* __restrict__ pair,
                                              const s16* __restrict__ WT,
                                              const float* __restrict__ bias,
                                              s16* __restrict__ outT) {
    __shared__ __align__(16) s16 As[128 * 128];  // 32KB, XOR-swizzled rows (256B)
    const int t = threadIdx.x;
    const int b = blockIdx.x;
    const int c0 = b & 511, rb = b >> 9;
    {
        const int p = t >> 1;
        const int dh = (t & 1) << 6;
        long gpos = COLMODE ? ((long)(rb * 128 + p) * 512 + c0) : ((long)b * 128 + p);
        const float* src = pair + gpos * 128 + dh;
        const int swz = (p & 7) << 4;
        char* lrow = (char*)As + p * 256;
#pragma unroll
        for (int g = 0; g < 8; ++g) {
            f32x4 v0 = *(const f32x4*)(src + g * 8);
            f32x4 v1 = *(const f32x4*)(src + g * 8 + 4);
            s16x8 pk;
            pk[0] = f2bf(v0[0]); pk[1] = f2bf(v0[1]); pk[2] = f2bf(v0[2]); pk[3] = f2bf(v0[3]);
            pk[4] = f2bf(v1[0]); pk[5] = f2bf(v1[1]); pk[6] = f2bf(v1[2]); pk[7] = f2bf(v1[3]);
            *(s16x8*)(lrow + ((dh * 2 + g * 16) ^ swz)) = pk;
        }
    }
    __syncthreads();
    const int w = t >> 6, l = t & 63;
    const int wr = (w >> 1) * 64, wc = (w & 1) * 64;
    const int lr = l & 15, lg = l >> 4;
    f32x4 acc[4][4];
#pragma unroll
    for (int mi = 0; mi < 4; ++mi)
#pragma unroll
        for (int ni = 0; ni < 4; ++ni) acc[mi][ni] = (f32x4){0.f, 0.f, 0.f, 0.f};
#pragma unroll
    for (int ks = 0; ks < 4; ++ks) {
        const int kk = ks * 32 + lg * 8;
        s16x8 af[4], bfv[4];
#pragma unroll
        for (int mi = 0; mi < 4; ++mi) {
            int row = wr + mi * 16 + lr;
            af[mi] = *(const s16x8*)((const char*)As + ((row * 256 + kk * 2) ^ ((row & 7) << 4)));
        }
#pragma unroll
        for (int ni = 0; ni < 4; ++ni) {
            int h = wc + ni * 16 + lr;
            bfv[ni] = *(const s16x8*)(WT + h * 128 + kk);
        }
#pragma unroll
        for (int mi = 0; mi < 4; ++mi)
#pragma unroll
            for (int ni = 0; ni < 4; ++ni)
                acc[mi][ni] = __builtin_amdgcn_mfma_f32_16x16x32_bf16(af[mi], bfv[ni], acc[mi][ni], 0, 0, 0);
    }
#pragma unroll
    for (int ni = 0; ni < 4; ++ni) {
        const int h = wc + ni * 16 + lr;
        const float bv = bias[h];
        long base = (long)h * NPOS + (COLMODE ? ((long)c0 * 512 + rb * 128) : ((long)b * 128));
#pragma unroll
        for (int mi = 0; mi < 4; ++mi) {
            const int prow = wr + mi * 16 + lg * 4;
            s16x4 pk;
#pragma unroll
            for (int r = 0; r < 4; ++r) pk[r] = f2bf(acc[mi][ni][r] + bv);
            *(s16x4*)(outT + base + prow) = pk;
        }
    }
}

// ---------------- K2: triangle einsum = 128 batched 512^3 GEMMs ----------------
__global__ __launch_bounds__(256) void k_tri(const s16* __restrict__ leftT,
                                             const s16* __restrict__ rightTT,
                                             s16* __restrict__ tri) {
    __shared__ __align__(16) s16 As[128 * 64];
    __shared__ __align__(16) s16 Bs[128 * 64];
    const int t = threadIdx.x;
    const int logical = ((blockIdx.x & 7) << 8) | (blockIdx.x >> 3);
    const int h = logical >> 4;
    const int ti = (logical >> 2) & 3, tj = logical & 3;
    const s16* Ap = leftT + (long)h * NPOS + ti * 128 * 512;
    const s16* Bp = rightTT + (long)h * NPOS + tj * 128 * 512;
    const int w = t >> 6, l = t & 63;
    const int wr = (w >> 1) * 64, wc = (w & 1) * 64;
    const int lr = l & 15, lg = l >> 4;
    const int srow = t >> 3;
    const int skk = (t & 7) << 3;
    f32x4 acc[4][4];
#pragma unroll
    for (int mi = 0; mi < 4; ++mi)
#pragma unroll
        for (int ni = 0; ni < 4; ++ni) acc[mi][ni] = (f32x4){0.f, 0.f, 0.f, 0.f};
    for (int kb = 0; kb < 512; kb += 64) {
        __syncthreads();
#pragma unroll
        for (int P = 0; P < 4; ++P) {
            int row = P * 32 + srow;
            int kks = skk ^ ((row & 7) << 3);
            unsigned loff = P * 4096 + w * 1024;
            gload_lds16(Ap + row * 512 + kb + kks, (char*)As + loff);
            gload_lds16(Bp + row * 512 + kb + kks, (char*)Bs + loff);
        }
        __syncthreads();
#pragma unroll
        for (int ks = 0; ks < 2; ++ks) {
            const int kk = ks * 32 + lg * 8;
            s16x8 af[4], bfv[4];
#pragma unroll
            for (int mi = 0; mi < 4; ++mi) {
                int row = wr + mi * 16 + lr;
                af[mi] = *(const s16x8*)((const char*)As + ((row * 128 + kk * 2) ^ ((row & 7) << 4)));
            }
#pragma unroll
            for (int ni = 0; ni < 4; ++ni) {
                int row = wc + ni * 16 + lr;
                bfv[ni] = *(const s16x8*)((const char*)Bs + ((row * 128 + kk * 2) ^ ((row & 7) << 4)));
            }
#pragma unroll
            for (int mi = 0; mi < 4; ++mi)
#pragma unroll
                for (int ni = 0; ni < 4; ++ni)
                    acc[mi][ni] = __builtin_amdgcn_mfma_f32_16x16x32_bf16(af[mi], bfv[ni], acc[mi][ni], 0, 0, 0);
        }
    }
#pragma unroll
    for (int mi = 0; mi < 4; ++mi) {
#pragma unroll
        for (int r = 0; r < 4; ++r) {
            int i = ti * 128 + wr + mi * 16 + lg * 4 + r;
            s16* dst = tri + (long)h * NPOS + (long)i * 512 + tj * 128 + wc;
#pragma unroll
            for (int ni = 0; ni < 4; ++ni) dst[ni * 16 + lr] = f2bf(acc[mi][ni][r]);
        }
    }
}

// ---------------- K2b: transpose tri[h][pos] -> triT[pos][h] ----------------
__global__ __launch_bounds__(256) void k_trT(const s16* __restrict__ tri,
                                             s16* __restrict__ triT) {
    __shared__ __align__(16) s16 Ts[128 * 256];  // 64KB, [h][pos] swizzled
    const int t = threadIdx.x;
    const int w = t >> 6;
    const long posBase = (long)blockIdx.x * 256;
#pragma unroll
    for (int P = 0; P < 16; ++P) {
        const int S = P * 256 + t;
        const int h = S >> 5, u = S & 31;
        const int ug = u ^ ((h >> 3) & 7);
        gload_lds16(tri + (long)h * NPOS + posBase + (ug << 3),
                    (char*)Ts + (P * 256 + w * 64) * 16);
    }
    __syncthreads();
    const int hc = t & 15;
    const int pr = t >> 4;
    const int g = hc & 7;
#pragma unroll
    for (int it = 0; it < 16; ++it) {
        const int p = pr + it * 16;
        const int pu = (p >> 3) ^ g, po = p & 7;
        s16x8 pk;
#pragma unroll
        for (int j = 0; j < 8; ++j)
            pk[j] = Ts[(hc * 8 + j) * 256 + pu * 8 + po];
        *(s16x8*)(triT + (posBase + p) * 128 + hc * 8) = pk;
    }
}

// ---------------- K3 v6: C^T formulation — weights live in registers ----------------
// Wave w owns d-stripe [16w,16w+16). accO/accG = W^T(stripe) @ X^T; B-frags are
// row-major s16x8 loads of triT/pair. LN via 8.4KB LDS x-buffer; raw s_barrier
// + lgkmcnt only (no vmcnt drain -> loads/stores stay in flight across barriers).
struct Frag {
    s16x8 tb[4];  // triT B-frags
    s16x8 pb[4];  // pair B-frags (bf16, converted at load)
    f32x4 rs;     // residual pair[pos][dl..dl+4]
};

__global__ __launch_bounds__(512, 4) void k_final(const float* __restrict__ pair,
                                                  const s16* __restrict__ triT,
                                                  const s16* __restrict__ WgT,
                                                  const s16* __restrict__ WoT,
                                                  const float* __restrict__ bgv,
                                                  const float* __restrict__ bov,
                                                  const float* __restrict__ gam,
                                                  const float* __restrict__ bet,
                                                  float* __restrict__ out) {
    __shared__ __align__(16) float xbuf[16][132];
    const int t = threadIdx.x;
    const int w = t >> 6, l = t & 63;
    const int lr = l & 15, lg = l >> 4;
    const int d0 = w << 4;        // wave's d-stripe
    const int dl = d0 + lg * 4;   // lane's d base in epilogue
    // weights: loaded ONCE, resident all kernel (A-operand of both GEMMs)
    s16x8 wo[4], wg[4];
#pragma unroll
    for (int ks = 0; ks < 4; ++ks) {
        const int kk = ks * 32 + lg * 8;
        wo[ks] = *(const s16x8*)(WoT + (d0 + lr) * 128 + kk);
        wg[ks] = *(const s16x8*)(WgT + (d0 + lr) * 128 + kk);
    }
    const f32x4 bo4 = *(const f32x4*)(bov + dl);
    const f32x4 bg4 = *(const f32x4*)(bgv + dl);
    const int lnp = t >> 5;          // LN: pos row 0..15
    const int lnd = (t & 31) * 4;    // LN: d chunk
    const f32x4 gm4 = *(const f32x4*)(gam + lnd);
    const f32x4 bt4 = *(const f32x4*)(bet + lnd);

    auto loadFrag = [&](Frag& f, long tile) {
        const long pos = tile * 16 + lr;
        const s16* tr = triT + pos * 128;
        const float* pr = pair + pos * 128;
#pragma unroll
        for (int ks = 0; ks < 4; ++ks) {
            const int kk = ks * 32 + lg * 8;
            f.tb[ks] = *(const s16x8*)(tr + kk);
            f32x4 a = *(const f32x4*)(pr + kk);
            f32x4 b = *(const f32x4*)(pr + kk + 4);
            s16x8 pb;
            pb[0] = f2bf(a[0]); pb[1] = f2bf(a[1]); pb[2] = f2bf(a[2]); pb[3] = f2bf(a[3]);
            pb[4] = f2bf(b[0]); pb[5] = f2bf(b[1]); pb[6] = f2bf(b[2]); pb[7] = f2bf(b[3]);
            f.pb[ks] = pb;
        }
        f.rs = *(const f32x4*)(pr + dl);
    };

    auto processTile = [&](const Frag& f, long tile) {
        f32x4 accO = (f32x4){0.f, 0.f, 0.f, 0.f};
        f32x4 accG = (f32x4){0.f, 0.f, 0.f, 0.f};
#pragma unroll
        for (int ks = 0; ks < 4; ++ks) {
            accO = __builtin_amdgcn_mfma_f32_16x16x32_bf16(wo[ks], f.tb[ks], accO, 0, 0, 0);
            accG = __builtin_amdgcn_mfma_f32_16x16x32_bf16(wg[ks], f.pb[ks], accG, 0, 0, 0);
        }
        // epilogue: D col=lr -> pos = tile*16+lr ; row=lg*4+r -> d = dl+r
        f32x4 xr;
#pragma unroll
        for (int r = 0; r < 4; ++r) {
            const float gate = 1.f / (1.f + __expf(-(accG[r] + bg4[r])));
            xr[r] = f.rs[r] + gate * (accO[r] + bo4[r]);
        }
        *(f32x4*)&xbuf[lr][dl] = xr;
        asm volatile("s_waitcnt lgkmcnt(0)" ::: "memory");
        __builtin_amdgcn_s_barrier();
        __builtin_amdgcn_sched_barrier(0);
        // LN: thread t owns (pos=lnp, d=lnd..lnd+3); reduce over 32 lanes
        f32x4 xv = *(const f32x4*)&xbuf[lnp][lnd];
        float s = xv[0] + xv[1] + xv[2] + xv[3];
        s += __shfl_xor(s, 1); s += __shfl_xor(s, 2); s += __shfl_xor(s, 4);
        s += __shfl_xor(s, 8); s += __shfl_xor(s, 16);
        const float mu = s * 0.0078125f;
        float v = 0.f;
#pragma unroll
        for (int j = 0; j < 4; ++j) { float dd = xv[j] - mu; v += dd * dd; }
        v += __shfl_xor(v, 1); v += __shfl_xor(v, 2); v += __shfl_xor(v, 4);
        v += __shfl_xor(v, 8); v += __shfl_xor(v, 16);
        const float rstd = rsqrtf(v * 0.0078125f + 1e-5f);
        f32x4 o;
#pragma unroll
        for (int j = 0; j < 4; ++j) o[j] = (xv[j] - mu) * rstd * gm4[j] + bt4[j];
        *(f32x4*)(out + (tile * 16 + lnp) * 128 + lnd) = o;
        asm volatile("s_waitcnt lgkmcnt(0)" ::: "memory");
        __builtin_amdgcn_s_barrier();
        __builtin_amdgcn_sched_barrier(0);
    };

    const long tb0 = (long)blockIdx.x * 8;
    Frag fA, fB;
    loadFrag(fA, tb0 + 0);
    loadFrag(fB, tb0 + 1);
#pragma unroll
    for (int ii = 0; ii < 4; ++ii) {
        processTile(fA, tb0 + ii * 2);
        if (ii < 3) loadFrag(fA, tb0 + ii * 2 + 2);
        processTile(fB, tb0 + ii * 2 + 1);
        if (ii < 3) loadFrag(fB, tb0 + ii * 2 + 3);
    }
}

extern "C" void kernel_launch(void* const* d_in, const int* in_sizes, int n_in,
                              void* d_out, int out_size, void* d_ws, size_t ws_size,
                              hipStream_t stream) {
    const float* pair = (const float*)d_in[0];
    const float* Wl   = (const float*)d_in[1];
    const float* bl   = (const float*)d_in[2];
    const float* Wr   = (const float*)d_in[3];
    const float* br   = (const float*)d_in[4];
    const float* Wo   = (const float*)d_in[5];
    const float* bo   = (const float*)d_in[6];
    const float* Wg   = (const float*)d_in[7];
    const float* bg   = (const float*)d_in[8];
    const float* gam  = (const float*)d_in[9];
    const float* bet  = (const float*)d_in[10];
    float* out = (float*)d_out;

    s16* WlT = (s16*)d_ws;
    s16* WrT = WlT + 128 * 128;
    s16* WgT = WrT + 128 * 128;
    s16* WoT = WgT + 128 * 128;
    s16* leftT   = WoT + 128 * 128;            // [128][NPOS]; becomes triT after k_tri
    s16* rightTT = leftT + (long)128 * NPOS;   // [128][NPOS]
    s16* tri     = rightTT + (long)128 * NPOS; // [128][NPOS]
    s16* triT    = leftT;                      // [NPOS][128]

    k_prep<<<4, 256, 0, stream>>>(Wl, Wr, Wg, Wo, WlT, WrT, WgT, WoT);
    k_proj<0><<<2048, 256, 0, stream>>>(pair, WlT, bl, leftT);
    k_proj<1><<<2048, 256, 0, stream>>>(pair, WrT, br, rightTT);
    k_tri<<<2048, 256, 0, stream>>>(leftT, rightTT, tri);
    k_trT<<<1024, 256, 0, stream>>>(tri, triT);
    k_final<<<2048, 512, 0, stream>>>(pair, triT, WgT, WoT, bg, bo, gam, bet, out);
}

// Round 7
// 445.131 us; speedup vs baseline: 1.5241x; 1.5241x over previous
//
#include <hip/hip_runtime.h>
#include <hip/hip_bf16.h>

// TriangleMultiplication on MI355X (gfx950).
// Pipeline: k_prep ; k_proj<0> (leftT) ; k_proj<1> (rightTT) ; k_tri (tri[h][pos]) ;
//           k_trT (tri -> triT[pos][h]) ; k_final v7 (C^T form, straight-line, no spill).
// ws layout: WlT|WrT|WgT|WoT (4*32KB) + leftT/triT (64MB) + rightTT (64MB) + tri (64MB)

#define LSZ 512
#define NPOS (LSZ * LSZ)  // 262144 positions

typedef short s16;
typedef __attribute__((ext_vector_type(4))) short s16x4;
typedef __attribute__((ext_vector_type(8))) short s16x8;
typedef __attribute__((ext_vector_type(4))) float f32x4;

typedef const __attribute__((address_space(1))) unsigned int* gas1;
typedef __attribute__((address_space(3))) unsigned int* las3;

static __device__ __forceinline__ s16 f2bf(float f) {
    unsigned int u = __builtin_bit_cast(unsigned int, f);
    u += 0x7FFFu + ((u >> 16) & 1u);
    return (s16)(u >> 16);
}

static __device__ __forceinline__ void gload_lds16(const void* g, void* l) {
    __builtin_amdgcn_global_load_lds((gas1)g, (las3)l, 16, 0, 0);
}

// ---------------- K0: transpose weights to bf16 [out][in] ----------------
__global__ void k_prep(const float* __restrict__ Wl, const float* __restrict__ Wr,
                       const float* __restrict__ Wg, const float* __restrict__ Wo,
                       s16* __restrict__ WlT, s16* __restrict__ WrT,
                       s16* __restrict__ WgT, s16* __restrict__ WoT) {
    const float* src;
    s16* dst;
    switch (blockIdx.x) {
        case 0: src = Wl; dst = WlT; break;
        case 1: src = Wr; dst = WrT; break;
        case 2: src = Wg; dst = WgT; break;
        default: src = Wo; dst = WoT; break;
    }
    for (int e = threadIdx.x; e < 128 * 128; e += blockDim.x) {
        int o = e >> 7, i = e & 127;
        dst[e] = f2bf(src[i * 128 + o]);  // WT[o][i] = W[i][o]
    }
}

// ---------------- K1: projection GEMM, output transposed [h][pos] ----------------
template <int COLMODE>
__global__ __launch_bounds__(256) void k_proj(const float* __restrict__ pair,
                                              const s16* __restrict__ WT,
                                              const float* __restrict__ bias,
                                              s16* __restrict__ outT) {
    __shared__ __align__(16) s16 As[128 * 128];  // 32KB, XOR-swizzled rows (256B)
    const int t = threadIdx.x;
    const int b = blockIdx.x;
    const int c0 = b & 511, rb = b >> 9;
    {
        const int p = t >> 1;
        const int dh = (t & 1) << 6;
        long gpos = COLMODE ? ((long)(rb * 128 + p) * 512 + c0) : ((long)b * 128 + p);
        const float* src = pair + gpos * 128 + dh;
        const int swz = (p & 7) << 4;
        char* lrow = (char*)As + p * 256;
#pragma unroll
        for (int g = 0; g < 8; ++g) {
            f32x4 v0 = *(const f32x4*)(src + g * 8);
            f32x4 v1 = *(const f32x4*)(src + g * 8 + 4);
            s16x8 pk;
            pk[0] = f2bf(v0[0]); pk[1] = f2bf(v0[1]); pk[2] = f2bf(v0[2]); pk[3] = f2bf(v0[3]);
            pk[4] = f2bf(v1[0]); pk[5] = f2bf(v1[1]); pk[6] = f2bf(v1[2]); pk[7] = f2bf(v1[3]);
            *(s16x8*)(lrow + ((dh * 2 + g * 16) ^ swz)) = pk;
        }
    }
    __syncthreads();
    const int w = t >> 6, l = t & 63;
    const int wr = (w >> 1) * 64, wc = (w & 1) * 64;
    const int lr = l & 15, lg = l >> 4;
    f32x4 acc[4][4];
#pragma unroll
    for (int mi = 0; mi < 4; ++mi)
#pragma unroll
        for (int ni = 0; ni < 4; ++ni) acc[mi][ni] = (f32x4){0.f, 0.f, 0.f, 0.f};
#pragma unroll
    for (int ks = 0; ks < 4; ++ks) {
        const int kk = ks * 32 + lg * 8;
        s16x8 af[4], bfv[4];
#pragma unroll
        for (int mi = 0; mi < 4; ++mi) {
            int row = wr + mi * 16 + lr;
            af[mi] = *(const s16x8*)((const char*)As + ((row * 256 + kk * 2) ^ ((row & 7) << 4)));
        }
#pragma unroll
        for (int ni = 0; ni < 4; ++ni) {
            int h = wc + ni * 16 + lr;
            bfv[ni] = *(const s16x8*)(WT + h * 128 + kk);
        }
#pragma unroll
        for (int mi = 0; mi < 4; ++mi)
#pragma unroll
            for (int ni = 0; ni < 4; ++ni)
                acc[mi][ni] = __builtin_amdgcn_mfma_f32_16x16x32_bf16(af[mi], bfv[ni], acc[mi][ni], 0, 0, 0);
    }
#pragma unroll
    for (int ni = 0; ni < 4; ++ni) {
        const int h = wc + ni * 16 + lr;
        const float bv = bias[h];
        long base = (long)h * NPOS + (COLMODE ? ((long)c0 * 512 + rb * 128) : ((long)b * 128));
#pragma unroll
        for (int mi = 0; mi < 4; ++mi) {
            const int prow = wr + mi * 16 + lg * 4;
            s16x4 pk;
#pragma unroll
            for (int r = 0; r < 4; ++r) pk[r] = f2bf(acc[mi][ni][r] + bv);
            *(s16x4*)(outT + base + prow) = pk;
        }
    }
}

// ---------------- K2: triangle einsum = 128 batched 512^3 GEMMs ----------------
__global__ __launch_bounds__(256) void k_tri(const s16* __restrict__ leftT,
                                             const s16* __restrict__ rightTT,
                                             s16* __restrict__ tri) {
    __shared__ __align__(16) s16 As[128 * 64];
    __shared__ __align__(16) s16 Bs[128 * 64];
    const int t = threadIdx.x;
    const int logical = ((blockIdx.x & 7) << 8) | (blockIdx.x >> 3);
    const int h = logical >> 4;
    const int ti = (logical >> 2) & 3, tj = logical & 3;
    const s16* Ap = leftT + (long)h * NPOS + ti * 128 * 512;
    const s16* Bp = rightTT + (long)h * NPOS + tj * 128 * 512;
    const int w = t >> 6, l = t & 63;
    const int wr = (w >> 1) * 64, wc = (w & 1) * 64;
    const int lr = l & 15, lg = l >> 4;
    const int srow = t >> 3;
    const int skk = (t & 7) << 3;
    f32x4 acc[4][4];
#pragma unroll
    for (int mi = 0; mi < 4; ++mi)
#pragma unroll
        for (int ni = 0; ni < 4; ++ni) acc[mi][ni] = (f32x4){0.f, 0.f, 0.f, 0.f};
    for (int kb = 0; kb < 512; kb += 64) {
        __syncthreads();
#pragma unroll
        for (int P = 0; P < 4; ++P) {
            int row = P * 32 + srow;
            int kks = skk ^ ((row & 7) << 3);
            unsigned loff = P * 4096 + w * 1024;
            gload_lds16(Ap + row * 512 + kb + kks, (char*)As + loff);
            gload_lds16(Bp + row * 512 + kb + kks, (char*)Bs + loff);
        }
        __syncthreads();
#pragma unroll
        for (int ks = 0; ks < 2; ++ks) {
            const int kk = ks * 32 + lg * 8;
            s16x8 af[4], bfv[4];
#pragma unroll
            for (int mi = 0; mi < 4; ++mi) {
                int row = wr + mi * 16 + lr;
                af[mi] = *(const s16x8*)((const char*)As + ((row * 128 + kk * 2) ^ ((row & 7) << 4)));
            }
#pragma unroll
            for (int ni = 0; ni < 4; ++ni) {
                int row = wc + ni * 16 + lr;
                bfv[ni] = *(const s16x8*)((const char*)Bs + ((row * 128 + kk * 2) ^ ((row & 7) << 4)));
            }
#pragma unroll
            for (int mi = 0; mi < 4; ++mi)
#pragma unroll
                for (int ni = 0; ni < 4; ++ni)
                    acc[mi][ni] = __builtin_amdgcn_mfma_f32_16x16x32_bf16(af[mi], bfv[ni], acc[mi][ni], 0, 0, 0);
        }
    }
#pragma unroll
    for (int mi = 0; mi < 4; ++mi) {
#pragma unroll
        for (int r = 0; r < 4; ++r) {
            int i = ti * 128 + wr + mi * 16 + lg * 4 + r;
            s16* dst = tri + (long)h * NPOS + (long)i * 512 + tj * 128 + wc;
#pragma unroll
            for (int ni = 0; ni < 4; ++ni) dst[ni * 16 + lr] = f2bf(acc[mi][ni][r]);
        }
    }
}

// ---------------- K2b: transpose tri[h][pos] -> triT[pos][h] ----------------
__global__ __launch_bounds__(256) void k_trT(const s16* __restrict__ tri,
                                             s16* __restrict__ triT) {
    __shared__ __align__(16) s16 Ts[128 * 256];  // 64KB, [h][pos] swizzled
    const int t = threadIdx.x;
    const int w = t >> 6;
    const long posBase = (long)blockIdx.x * 256;
#pragma unroll
    for (int P = 0; P < 16; ++P) {
        const int S = P * 256 + t;
        const int h = S >> 5, u = S & 31;
        const int ug = u ^ ((h >> 3) & 7);
        gload_lds16(tri + (long)h * NPOS + posBase + (ug << 3),
                    (char*)Ts + (P * 256 + w * 64) * 16);
    }
    __syncthreads();
    const int hc = t & 15;
    const int pr = t >> 4;
    const int g = hc & 7;
#pragma unroll
    for (int it = 0; it < 16; ++it) {
        const int p = pr + it * 16;
        const int pu = (p >> 3) ^ g, po = p & 7;
        s16x8 pk;
#pragma unroll
        for (int j = 0; j < 8; ++j)
            pk[j] = Ts[(hc * 8 + j) * 256 + pu * 8 + po];
        *(s16x8*)(triT + (posBase + p) * 128 + hc * 8) = pk;
    }
}

// ---------------- K3 v7: C^T form, straight-line, spill-free ----------------
// Wave w owns d-stripe [16w,16w+16): weights (A-operand) resident in 32 regs.
// Per 16-pos tile: 13 independent coalesced loads -> 8 MFMAs -> gate/residual
// -> xbuf -> LN -> coalesced store. Latency hidden by occupancy (VGPR<=128).
#define FT 4
__global__ __launch_bounds__(512, 4) void k_final(const float* __restrict__ pair,
                                                  const s16* __restrict__ triT,
                                                  const s16* __restrict__ WgT,
                                                  const s16* __restrict__ WoT,
                                                  const float* __restrict__ bgv,
                                                  const float* __restrict__ bov,
                                                  const float* __restrict__ gam,
                                                  const float* __restrict__ bet,
                                                  float* __restrict__ out) {
    __shared__ __align__(16) float xbuf[16][132];
    const int t = threadIdx.x;
    const int w = t >> 6, l = t & 63;
    const int lr = l & 15, lg = l >> 4;
    const int d0 = w << 4;       // wave's d-stripe
    const int dl = d0 + lg * 4;  // lane's d base (epilogue rows)
    // weights: loaded ONCE, A-operand of both GEMMs (32 VGPRs)
    s16x8 wo0, wo1, wo2, wo3, wg0, wg1, wg2, wg3;
    {
        const s16* wop = WoT + (d0 + lr) * 128 + lg * 8;
        const s16* wgp = WgT + (d0 + lr) * 128 + lg * 8;
        wo0 = *(const s16x8*)(wop);       wg0 = *(const s16x8*)(wgp);
        wo1 = *(const s16x8*)(wop + 32);  wg1 = *(const s16x8*)(wgp + 32);
        wo2 = *(const s16x8*)(wop + 64);  wg2 = *(const s16x8*)(wgp + 64);
        wo3 = *(const s16x8*)(wop + 96);  wg3 = *(const s16x8*)(wgp + 96);
    }
    const f32x4 bo4 = *(const f32x4*)(bov + dl);
    const f32x4 bg4 = *(const f32x4*)(bgv + dl);
    const int lnp = t >> 5;        // LN: pos row 0..15
    const int lnd = (t & 31) * 4;  // LN: d chunk
    const f32x4 gm4 = *(const f32x4*)(gam + lnd);
    const f32x4 bt4 = *(const f32x4*)(bet + lnd);

    for (int it = 0; it < FT; ++it) {
        const long tile = (long)blockIdx.x * FT + it;
        const long pos = tile * 16 + lr;
        const s16* tr = triT + pos * 128 + lg * 8;
        const float* pr = pair + pos * 128 + lg * 8;
        // 13 independent loads (compiler issues together, one waitcnt)
        s16x8 tb0 = *(const s16x8*)(tr);
        s16x8 tb1 = *(const s16x8*)(tr + 32);
        s16x8 tb2 = *(const s16x8*)(tr + 64);
        s16x8 tb3 = *(const s16x8*)(tr + 96);
        f32x4 a0 = *(const f32x4*)(pr);       f32x4 b0 = *(const f32x4*)(pr + 4);
        f32x4 a1 = *(const f32x4*)(pr + 32);  f32x4 b1 = *(const f32x4*)(pr + 36);
        f32x4 a2 = *(const f32x4*)(pr + 64);  f32x4 b2 = *(const f32x4*)(pr + 68);
        f32x4 a3 = *(const f32x4*)(pr + 96);  f32x4 b3 = *(const f32x4*)(pr + 100);
        const f32x4 rs = *(const f32x4*)(pair + pos * 128 + dl);
        s16x8 pb0, pb1, pb2, pb3;
        pb0[0] = f2bf(a0[0]); pb0[1] = f2bf(a0[1]); pb0[2] = f2bf(a0[2]); pb0[3] = f2bf(a0[3]);
        pb0[4] = f2bf(b0[0]); pb0[5] = f2bf(b0[1]); pb0[6] = f2bf(b0[2]); pb0[7] = f2bf(b0[3]);
        pb1[0] = f2bf(a1[0]); pb1[1] = f2bf(a1[1]); pb1[2] = f2bf(a1[2]); pb1[3] = f2bf(a1[3]);
        pb1[4] = f2bf(b1[0]); pb1[5] = f2bf(b1[1]); pb1[6] = f2bf(b1[2]); pb1[7] = f2bf(b1[3]);
        pb2[0] = f2bf(a2[0]); pb2[1] = f2bf(a2[1]); pb2[2] = f2bf(a2[2]); pb2[3] = f2bf(a2[3]);
        pb2[4] = f2bf(b2[0]); pb2[5] = f2bf(b2[1]); pb2[6] = f2bf(b2[2]); pb2[7] = f2bf(b2[3]);
        pb3[0] = f2bf(a3[0]); pb3[1] = f2bf(a3[1]); pb3[2] = f2bf(a3[2]); pb3[3] = f2bf(a3[3]);
        pb3[4] = f2bf(b3[0]); pb3[5] = f2bf(b3[1]); pb3[6] = f2bf(b3[2]); pb3[7] = f2bf(b3[3]);
        // 8 MFMAs
        f32x4 accO = (f32x4){0.f, 0.f, 0.f, 0.f};
        f32x4 accG = (f32x4){0.f, 0.f, 0.f, 0.f};
        accO = __builtin_amdgcn_mfma_f32_16x16x32_bf16(wo0, tb0, accO, 0, 0, 0);
        accG = __builtin_amdgcn_mfma_f32_16x16x32_bf16(wg0, pb0, accG, 0, 0, 0);
        accO = __builtin_amdgcn_mfma_f32_16x16x32_bf16(wo1, tb1, accO, 0, 0, 0);
        accG = __builtin_amdgcn_mfma_f32_16x16x32_bf16(wg1, pb1, accG, 0, 0, 0);
        accO = __builtin_amdgcn_mfma_f32_16x16x32_bf16(wo2, tb2, accO, 0, 0, 0);
        accG = __builtin_amdgcn_mfma_f32_16x16x32_bf16(wg2, pb2, accG, 0, 0, 0);
        accO = __builtin_amdgcn_mfma_f32_16x16x32_bf16(wo3, tb3, accO, 0, 0, 0);
        accG = __builtin_amdgcn_mfma_f32_16x16x32_bf16(wg3, pb3, accG, 0, 0, 0);
        // gate + residual ; D: col=lr -> pos, row=lg*4+r -> d=dl+r
        f32x4 xr;
#pragma unroll
        for (int r = 0; r < 4; ++r) {
            const float gate = 1.f / (1.f + __expf(-(accG[r] + bg4[r])));
            xr[r] = rs[r] + gate * (accO[r] + bo4[r]);
        }
        *(f32x4*)&xbuf[lr][dl] = xr;
        asm volatile("s_waitcnt lgkmcnt(0)" ::: "memory");
        __builtin_amdgcn_s_barrier();
        __builtin_amdgcn_sched_barrier(0);
        // LN: thread t owns (pos=lnp, d=lnd..lnd+3)
        f32x4 xv = *(const f32x4*)&xbuf[lnp][lnd];
        float s = xv[0] + xv[1] + xv[2] + xv[3];
        s += __shfl_xor(s, 1); s += __shfl_xor(s, 2); s += __shfl_xor(s, 4);
        s += __shfl_xor(s, 8); s += __shfl_xor(s, 16);
        const float mu = s * 0.0078125f;
        float v = 0.f;
#pragma unroll
        for (int j = 0; j < 4; ++j) { float dd = xv[j] - mu; v += dd * dd; }
        v += __shfl_xor(v, 1); v += __shfl_xor(v, 2); v += __shfl_xor(v, 4);
        v += __shfl_xor(v, 8); v += __shfl_xor(v, 16);
        const float rstd = rsqrtf(v * 0.0078125f + 1e-5f);
        f32x4 o;
#pragma unroll
        for (int j = 0; j < 4; ++j) o[j] = (xv[j] - mu) * rstd * gm4[j] + bt4[j];
        *(f32x4*)(out + (tile * 16 + lnp) * 128 + lnd) = o;
        __builtin_amdgcn_s_barrier();  // xbuf reuse guard (reads done before arrival)
    }
}

extern "C" void kernel_launch(void* const* d_in, const int* in_sizes, int n_in,
                              void* d_out, int out_size, void* d_ws, size_t ws_size,
                              hipStream_t stream) {
    const float* pair = (const float*)d_in[0];
    const float* Wl   = (const float*)d_in[1];
    const float* bl   = (const float*)d_in[2];
    const float* Wr   = (const float*)d_in[3];
    const float* br   = (const float*)d_in[4];
    const float* Wo   = (const float*)d_in[5];
    const float* bo   = (const float*)d_in[6];
    const float* Wg   = (const float*)d_in[7];
    const float* bg   = (const float*)d_in[8];
    const float* gam  = (const float*)d_in[9];
    const float* bet  = (const float*)d_in[10];
    float* out = (float*)d_out;

    s16* WlT = (s16*)d_ws;
    s16* WrT = WlT + 128 * 128;
    s16* WgT = WrT + 128 * 128;
    s16* WoT = WgT + 128 * 128;
    s16* leftT   = WoT + 128 * 128;            // [128][NPOS]; becomes triT after k_tri
    s16* rightTT = leftT + (long)128 * NPOS;   // [128][NPOS]
    s16* tri     = rightTT + (long)128 * NPOS; // [128][NPOS]
    s16* triT    = leftT;                      // [NPOS][128]

    k_prep<<<4, 256, 0, stream>>>(Wl, Wr, Wg, Wo, WlT, WrT, WgT, WoT);
    k_proj<0><<<2048, 256, 0, stream>>>(pair, WlT, bl, leftT);
    k_proj<1><<<2048, 256, 0, stream>>>(pair, WrT, br, rightTT);
    k_tri<<<2048, 256, 0, stream>>>(leftT, rightTT, tri);
    k_trT<<<1024, 256, 0, stream>>>(tri, triT);
    k_final<<<4096, 512, 0, stream>>>(pair, triT, WgT, WoT, bg, bo, gam, bet, out);
}

// Round 8
// 422.818 us; speedup vs baseline: 1.6045x; 1.0528x over previous
//
#include <hip/hip_runtime.h>
#include <hip/hip_bf16.h>

// TriangleMultiplication on MI355X (gfx950).
// Pipeline: k_prep ; k_proj<0> (leftT) ; k_proj<1> (rightTT) ; k_tri (tri[h][pos]) ;
//           k_trT (tri -> triT[pos][h]) ; k_final v8 (C^T form + 2-deep static pipeline).
// ws layout: WlT|WrT|WgT|WoT (4*32KB) + leftT/triT (64MB) + rightTT (64MB) + tri (64MB)

#define LSZ 512
#define NPOS (LSZ * LSZ)  // 262144 positions

typedef short s16;
typedef __attribute__((ext_vector_type(4))) short s16x4;
typedef __attribute__((ext_vector_type(8))) short s16x8;
typedef __attribute__((ext_vector_type(4))) float f32x4;

typedef const __attribute__((address_space(1))) unsigned int* gas1;
typedef __attribute__((address_space(3))) unsigned int* las3;

static __device__ __forceinline__ s16 f2bf(float f) {
    unsigned int u = __builtin_bit_cast(unsigned int, f);
    u += 0x7FFFu + ((u >> 16) & 1u);
    return (s16)(u >> 16);
}

static __device__ __forceinline__ void gload_lds16(const void* g, void* l) {
    __builtin_amdgcn_global_load_lds((gas1)g, (las3)l, 16, 0, 0);
}

// ---------------- K0: transpose weights to bf16 [out][in] ----------------
__global__ void k_prep(const float* __restrict__ Wl, const float* __restrict__ Wr,
                       const float* __restrict__ Wg, const float* __restrict__ Wo,
                       s16* __restrict__ WlT, s16* __restrict__ WrT,
                       s16* __restrict__ WgT, s16* __restrict__ WoT) {
    const float* src;
    s16* dst;
    switch (blockIdx.x) {
        case 0: src = Wl; dst = WlT; break;
        case 1: src = Wr; dst = WrT; break;
        case 2: src = Wg; dst = WgT; break;
        default: src = Wo; dst = WoT; break;
    }
    for (int e = threadIdx.x; e < 128 * 128; e += blockDim.x) {
        int o = e >> 7, i = e & 127;
        dst[e] = f2bf(src[i * 128 + o]);  // WT[o][i] = W[i][o]
    }
}

// ---------------- K1: projection GEMM, output transposed [h][pos] ----------------
template <int COLMODE>
__global__ __launch_bounds__(256) void k_proj(const float* __restrict__ pair,
                                              const s16* __restrict__ WT,
                                              const float* __restrict__ bias,
                                              s16* __restrict__ outT) {
    __shared__ __align__(16) s16 As[128 * 128];  // 32KB, XOR-swizzled rows (256B)
    const int t = threadIdx.x;
    const int b = blockIdx.x;
    const int c0 = b & 511, rb = b >> 9;
    {
        const int p = t >> 1;
        const int dh = (t & 1) << 6;
        long gpos = COLMODE ? ((long)(rb * 128 + p) * 512 + c0) : ((long)b * 128 + p);
        const float* src = pair + gpos * 128 + dh;
        const int swz = (p & 7) << 4;
        char* lrow = (char*)As + p * 256;
#pragma unroll
        for (int g = 0; g < 8; ++g) {
            f32x4 v0 = *(const f32x4*)(src + g * 8);
            f32x4 v1 = *(const f32x4*)(src + g * 8 + 4);
            s16x8 pk;
            pk[0] = f2bf(v0[0]); pk[1] = f2bf(v0[1]); pk[2] = f2bf(v0[2]); pk[3] = f2bf(v0[3]);
            pk[4] = f2bf(v1[0]); pk[5] = f2bf(v1[1]); pk[6] = f2bf(v1[2]); pk[7] = f2bf(v1[3]);
            *(s16x8*)(lrow + ((dh * 2 + g * 16) ^ swz)) = pk;
        }
    }
    __syncthreads();
    const int w = t >> 6, l = t & 63;
    const int wr = (w >> 1) * 64, wc = (w & 1) * 64;
    const int lr = l & 15, lg = l >> 4;
    f32x4 acc[4][4];
#pragma unroll
    for (int mi = 0; mi < 4; ++mi)
#pragma unroll
        for (int ni = 0; ni < 4; ++ni) acc[mi][ni] = (f32x4){0.f, 0.f, 0.f, 0.f};
#pragma unroll
    for (int ks = 0; ks < 4; ++ks) {
        const int kk = ks * 32 + lg * 8;
        s16x8 af[4], bfv[4];
#pragma unroll
        for (int mi = 0; mi < 4; ++mi) {
            int row = wr + mi * 16 + lr;
            af[mi] = *(const s16x8*)((const char*)As + ((row * 256 + kk * 2) ^ ((row & 7) << 4)));
        }
#pragma unroll
        for (int ni = 0; ni < 4; ++ni) {
            int h = wc + ni * 16 + lr;
            bfv[ni] = *(const s16x8*)(WT + h * 128 + kk);
        }
#pragma unroll
        for (int mi = 0; mi < 4; ++mi)
#pragma unroll
            for (int ni = 0; ni < 4; ++ni)
                acc[mi][ni] = __builtin_amdgcn_mfma_f32_16x16x32_bf16(af[mi], bfv[ni], acc[mi][ni], 0, 0, 0);
    }
#pragma unroll
    for (int ni = 0; ni < 4; ++ni) {
        const int h = wc + ni * 16 + lr;
        const float bv = bias[h];
        long base = (long)h * NPOS + (COLMODE ? ((long)c0 * 512 + rb * 128) : ((long)b * 128));
#pragma unroll
        for (int mi = 0; mi < 4; ++mi) {
            const int prow = wr + mi * 16 + lg * 4;
            s16x4 pk;
#pragma unroll
            for (int r = 0; r < 4; ++r) pk[r] = f2bf(acc[mi][ni][r] + bv);
            *(s16x4*)(outT + base + prow) = pk;
        }
    }
}

// ---------------- K2: triangle einsum = 128 batched 512^3 GEMMs ----------------
__global__ __launch_bounds__(256) void k_tri(const s16* __restrict__ leftT,
                                             const s16* __restrict__ rightTT,
                                             s16* __restrict__ tri) {
    __shared__ __align__(16) s16 As[128 * 64];
    __shared__ __align__(16) s16 Bs[128 * 64];
    const int t = threadIdx.x;
    const int logical = ((blockIdx.x & 7) << 8) | (blockIdx.x >> 3);
    const int h = logical >> 4;
    const int ti = (logical >> 2) & 3, tj = logical & 3;
    const s16* Ap = leftT + (long)h * NPOS + ti * 128 * 512;
    const s16* Bp = rightTT + (long)h * NPOS + tj * 128 * 512;
    const int w = t >> 6, l = t & 63;
    const int wr = (w >> 1) * 64, wc = (w & 1) * 64;
    const int lr = l & 15, lg = l >> 4;
    const int srow = t >> 3;
    const int skk = (t & 7) << 3;
    f32x4 acc[4][4];
#pragma unroll
    for (int mi = 0; mi < 4; ++mi)
#pragma unroll
        for (int ni = 0; ni < 4; ++ni) acc[mi][ni] = (f32x4){0.f, 0.f, 0.f, 0.f};
    for (int kb = 0; kb < 512; kb += 64) {
        __syncthreads();
#pragma unroll
        for (int P = 0; P < 4; ++P) {
            int row = P * 32 + srow;
            int kks = skk ^ ((row & 7) << 3);
            unsigned loff = P * 4096 + w * 1024;
            gload_lds16(Ap + row * 512 + kb + kks, (char*)As + loff);
            gload_lds16(Bp + row * 512 + kb + kks, (char*)Bs + loff);
        }
        __syncthreads();
#pragma unroll
        for (int ks = 0; ks < 2; ++ks) {
            const int kk = ks * 32 + lg * 8;
            s16x8 af[4], bfv[4];
#pragma unroll
            for (int mi = 0; mi < 4; ++mi) {
                int row = wr + mi * 16 + lr;
                af[mi] = *(const s16x8*)((const char*)As + ((row * 128 + kk * 2) ^ ((row & 7) << 4)));
            }
#pragma unroll
            for (int ni = 0; ni < 4; ++ni) {
                int row = wc + ni * 16 + lr;
                bfv[ni] = *(const s16x8*)((const char*)Bs + ((row * 128 + kk * 2) ^ ((row & 7) << 4)));
            }
#pragma unroll
            for (int mi = 0; mi < 4; ++mi)
#pragma unroll
                for (int ni = 0; ni < 4; ++ni)
                    acc[mi][ni] = __builtin_amdgcn_mfma_f32_16x16x32_bf16(af[mi], bfv[ni], acc[mi][ni], 0, 0, 0);
        }
    }
#pragma unroll
    for (int mi = 0; mi < 4; ++mi) {
#pragma unroll
        for (int r = 0; r < 4; ++r) {
            int i = ti * 128 + wr + mi * 16 + lg * 4 + r;
            s16* dst = tri + (long)h * NPOS + (long)i * 512 + tj * 128 + wc;
#pragma unroll
            for (int ni = 0; ni < 4; ++ni) dst[ni * 16 + lr] = f2bf(acc[mi][ni][r]);
        }
    }
}

// ---------------- K2b: transpose tri[h][pos] -> triT[pos][h] ----------------
__global__ __launch_bounds__(256) void k_trT(const s16* __restrict__ tri,
                                             s16* __restrict__ triT) {
    __shared__ __align__(16) s16 Ts[128 * 256];  // 64KB, [h][pos] swizzled
    const int t = threadIdx.x;
    const int w = t >> 6;
    const long posBase = (long)blockIdx.x * 256;
#pragma unroll
    for (int P = 0; P < 16; ++P) {
        const int S = P * 256 + t;
        const int h = S >> 5, u = S & 31;
        const int ug = u ^ ((h >> 3) & 7);
        gload_lds16(tri + (long)h * NPOS + posBase + (ug << 3),
                    (char*)Ts + (P * 256 + w * 64) * 16);
    }
    __syncthreads();
    const int hc = t & 15;
    const int pr = t >> 4;
    const int g = hc & 7;
#pragma unroll
    for (int it = 0; it < 16; ++it) {
        const int p = pr + it * 16;
        const int pu = (p >> 3) ^ g, po = p & 7;
        s16x8 pk;
#pragma unroll
        for (int j = 0; j < 8; ++j)
            pk[j] = Ts[(hc * 8 + j) * 256 + pu * 8 + po];
        *(s16x8*)(triT + (posBase + p) * 128 + hc * 8) = pk;
    }
}

// ---------------- K3 v8: C^T form + static 2-deep pipeline ----------------
// Per body: convert+MFMA set S -> xr -> REISSUE S's loads for tile+2 ->
// xbuf write -> lgkmcnt+barrier -> LN -> store. Loads stay in flight across the
// raw s_barrier (no vmcnt drain) and land ~2 phases later. xbuf double-buffered
// so there is ONE barrier per tile. All pipeline state in named scalars
// (rule #20: no runtime-indexed aggregates -> no scratch).
#define FT 8

#define LOADSET(S, TILE) do { \
    const long pos_ = (long)(TILE) * 16 + lr; \
    const s16* tr_ = triT + pos_ * 128 + (lg << 3); \
    const float* pr_ = pair + pos_ * 128 + (lg << 3); \
    S##tb0 = *(const s16x8*)(tr_); \
    S##tb1 = *(const s16x8*)(tr_ + 32); \
    S##tb2 = *(const s16x8*)(tr_ + 64); \
    S##tb3 = *(const s16x8*)(tr_ + 96); \
    S##a0 = *(const f32x4*)(pr_);       S##b0 = *(const f32x4*)(pr_ + 4); \
    S##a1 = *(const f32x4*)(pr_ + 32);  S##b1 = *(const f32x4*)(pr_ + 36); \
    S##a2 = *(const f32x4*)(pr_ + 64);  S##b2 = *(const f32x4*)(pr_ + 68); \
    S##a3 = *(const f32x4*)(pr_ + 96);  S##b3 = *(const f32x4*)(pr_ + 100); \
    S##rs = *(const f32x4*)(pair + pos_ * 128 + dl); \
} while (0)

#define CVT(dst, x, y) \
    dst[0] = f2bf(x[0]); dst[1] = f2bf(x[1]); dst[2] = f2bf(x[2]); dst[3] = f2bf(x[3]); \
    dst[4] = f2bf(y[0]); dst[5] = f2bf(y[1]); dst[6] = f2bf(y[2]); dst[7] = f2bf(y[3]);

#define BODY(S, TILE, BUF, DOPF, PFTILE) do { \
    s16x8 pb0_, pb1_, pb2_, pb3_; \
    CVT(pb0_, S##a0, S##b0) CVT(pb1_, S##a1, S##b1) \
    CVT(pb2_, S##a2, S##b2) CVT(pb3_, S##a3, S##b3) \
    f32x4 accO_ = (f32x4){0.f, 0.f, 0.f, 0.f}; \
    f32x4 accG_ = (f32x4){0.f, 0.f, 0.f, 0.f}; \
    accO_ = __builtin_amdgcn_mfma_f32_16x16x32_bf16(wo0, S##tb0, accO_, 0, 0, 0); \
    accG_ = __builtin_amdgcn_mfma_f32_16x16x32_bf16(wg0, pb0_, accG_, 0, 0, 0); \
    accO_ = __builtin_amdgcn_mfma_f32_16x16x32_bf16(wo1, S##tb1, accO_, 0, 0, 0); \
    accG_ = __builtin_amdgcn_mfma_f32_16x16x32_bf16(wg1, pb1_, accG_, 0, 0, 0); \
    accO_ = __builtin_amdgcn_mfma_f32_16x16x32_bf16(wo2, S##tb2, accO_, 0, 0, 0); \
    accG_ = __builtin_amdgcn_mfma_f32_16x16x32_bf16(wg2, pb2_, accG_, 0, 0, 0); \
    accO_ = __builtin_amdgcn_mfma_f32_16x16x32_bf16(wo3, S##tb3, accO_, 0, 0, 0); \
    accG_ = __builtin_amdgcn_mfma_f32_16x16x32_bf16(wg3, pb3_, accG_, 0, 0, 0); \
    f32x4 xr_; \
    _Pragma("unroll") \
    for (int r = 0; r < 4; ++r) { \
        const float gate_ = 1.f / (1.f + __expf(-(accG_[r] + bg4[r]))); \
        xr_[r] = S##rs[r] + gate_ * (accO_[r] + bo4[r]); \
    } \
    if (DOPF) { LOADSET(S, PFTILE); } \
    *(f32x4*)&xbuf[BUF][lr][dl] = xr_; \
    asm volatile("s_waitcnt lgkmcnt(0)" ::: "memory"); \
    __builtin_amdgcn_s_barrier(); \
    __builtin_amdgcn_sched_barrier(0); \
    f32x4 xv_ = *(const f32x4*)&xbuf[BUF][lnp][lnd]; \
    float s_ = xv_[0] + xv_[1] + xv_[2] + xv_[3]; \
    s_ += __shfl_xor(s_, 1); s_ += __shfl_xor(s_, 2); s_ += __shfl_xor(s_, 4); \
    s_ += __shfl_xor(s_, 8); s_ += __shfl_xor(s_, 16); \
    const float mu_ = s_ * 0.0078125f; \
    float v_ = 0.f; \
    _Pragma("unroll") \
    for (int j = 0; j < 4; ++j) { float dd_ = xv_[j] - mu_; v_ += dd_ * dd_; } \
    v_ += __shfl_xor(v_, 1); v_ += __shfl_xor(v_, 2); v_ += __shfl_xor(v_, 4); \
    v_ += __shfl_xor(v_, 8); v_ += __shfl_xor(v_, 16); \
    const float rstd_ = rsqrtf(v_ * 0.0078125f + 1e-5f); \
    f32x4 o_; \
    _Pragma("unroll") \
    for (int j = 0; j < 4; ++j) o_[j] = (xv_[j] - mu_) * rstd_ * gm4[j] + bt4[j]; \
    *(f32x4*)(out + ((long)(TILE) * 16 + lnp) * 128 + lnd) = o_; \
} while (0)

__global__ __launch_bounds__(512, 2) void k_final(const float* __restrict__ pair,
                                                  const s16* __restrict__ triT,
                                                  const s16* __restrict__ WgT,
                                                  const s16* __restrict__ WoT,
                                                  const float* __restrict__ bgv,
                                                  const float* __restrict__ bov,
                                                  const float* __restrict__ gam,
                                                  const float* __restrict__ bet,
                                                  float* __restrict__ out) {
    __shared__ __align__(16) float xbuf[2][16][132];  // 16.9KB, double-buffered
    const int t = threadIdx.x;
    const int w = t >> 6, l = t & 63;
    const int lr = l & 15, lg = l >> 4;
    const int d0 = w << 4;       // wave's d-stripe
    const int dl = d0 + lg * 4;  // lane's d base (epilogue rows)
    // weights: loaded ONCE, A-operand of both GEMMs (32 VGPRs)
    s16x8 wo0, wo1, wo2, wo3, wg0, wg1, wg2, wg3;
    {
        const s16* wop = WoT + (d0 + lr) * 128 + lg * 8;
        const s16* wgp = WgT + (d0 + lr) * 128 + lg * 8;
        wo0 = *(const s16x8*)(wop);       wg0 = *(const s16x8*)(wgp);
        wo1 = *(const s16x8*)(wop + 32);  wg1 = *(const s16x8*)(wgp + 32);
        wo2 = *(const s16x8*)(wop + 64);  wg2 = *(const s16x8*)(wgp + 64);
        wo3 = *(const s16x8*)(wop + 96);  wg3 = *(const s16x8*)(wgp + 96);
    }
    const f32x4 bo4 = *(const f32x4*)(bov + dl);
    const f32x4 bg4 = *(const f32x4*)(bgv + dl);
    const int lnp = t >> 5;        // LN: pos row 0..15
    const int lnd = (t & 31) * 4;  // LN: d chunk
    const f32x4 gm4 = *(const f32x4*)(gam + lnd);
    const f32x4 bt4 = *(const f32x4*)(bet + lnd);

    // pipeline register sets (named scalars only)
    s16x8 Atb0, Atb1, Atb2, Atb3, Btb0, Btb1, Btb2, Btb3;
    f32x4 Aa0, Aa1, Aa2, Aa3, Ab0, Ab1, Ab2, Ab3, Ars;
    f32x4 Ba0, Ba1, Ba2, Ba3, Bb0, Bb1, Bb2, Bb3, Brs;

    const long tb0 = (long)blockIdx.x * FT;
    LOADSET(A, tb0 + 0);
    LOADSET(B, tb0 + 1);
#pragma unroll
    for (int ii = 0; ii < FT / 2; ++ii) {
        BODY(A, tb0 + 2 * ii, 0, (2 * ii + 2 < FT), tb0 + 2 * ii + 2);
        BODY(B, tb0 + 2 * ii + 1, 1, (2 * ii + 3 < FT), tb0 + 2 * ii + 3);
    }
}

extern "C" void kernel_launch(void* const* d_in, const int* in_sizes, int n_in,
                              void* d_out, int out_size, void* d_ws, size_t ws_size,
                              hipStream_t stream) {
    const float* pair = (const float*)d_in[0];
    const float* Wl   = (const float*)d_in[1];
    const float* bl   = (const float*)d_in[2];
    const float* Wr   = (const float*)d_in[3];
    const float* br   = (const float*)d_in[4];
    const float* Wo   = (const float*)d_in[5];
    const float* bo   = (const float*)d_in[6];
    const float* Wg   = (const float*)d_in[7];
    const float* bg   = (const float*)d_in[8];
    const float* gam  = (const float*)d_in[9];
    const float* bet  = (const float*)d_in[10];
    float* out = (float*)d_out;

    s16* WlT = (s16*)d_ws;
    s16* WrT = WlT + 128 * 128;
    s16* WgT = WrT + 128 * 128;
    s16* WoT = WgT + 128 * 128;
    s16* leftT   = WoT + 128 * 128;            // [128][NPOS]; becomes triT after k_tri
    s16* rightTT = leftT + (long)128 * NPOS;   // [128][NPOS]
    s16* tri     = rightTT + (long)128 * NPOS; // [128][NPOS]
    s16* triT    = leftT;                      // [NPOS][128]

    k_prep<<<4, 256, 0, stream>>>(Wl, Wr, Wg, Wo, WlT, WrT, WgT, WoT);
    k_proj<0><<<2048, 256, 0, stream>>>(pair, WlT, bl, leftT);
    k_proj<1><<<2048, 256, 0, stream>>>(pair, WrT, br, rightTT);
    k_tri<<<2048, 256, 0, stream>>>(leftT, rightTT, tri);
    k_trT<<<1024, 256, 0, stream>>>(tri, triT);
    k_final<<<2048, 512, 0, stream>>>(pair, triT, WgT, WoT, bg, bo, gam, bet, out);
}

// Round 10
// 307.220 us; speedup vs baseline: 2.2082x; 1.3763x over previous
//
#include <hip/hip_runtime.h>
#include <hip/hip_bf16.h>

// TriangleMultiplication on MI355X (gfx950).
// Pipeline: k_prep ; k_proj<0> (leftT) ; k_proj<1> (rightTT) ; k_tri (tri[h][pos]) ;
//           k_trT (tri -> triT[pos][h]) ; k_final v9 (C^T + async LDS staging, counted vmcnt).
// ws layout: WlT|WrT|WgT|WoT (4*32KB) + leftT/triT (64MB) + rightTT (64MB) + tri (64MB)

#define LSZ 512
#define NPOS (LSZ * LSZ)  // 262144 positions

typedef short s16;
typedef __attribute__((ext_vector_type(4))) short s16x4;
typedef __attribute__((ext_vector_type(8))) short s16x8;
typedef __attribute__((ext_vector_type(4))) float f32x4;

typedef const __attribute__((address_space(1))) unsigned int* gas1;
typedef __attribute__((address_space(3))) unsigned int* las3;

static __device__ __forceinline__ s16 f2bf(float f) {
    unsigned int u = __builtin_bit_cast(unsigned int, f);
    u += 0x7FFFu + ((u >> 16) & 1u);
    return (s16)(u >> 16);
}

static __device__ __forceinline__ void gload_lds16(const void* g, void* l) {
    __builtin_amdgcn_global_load_lds((gas1)g, (las3)l, 16, 0, 0);
}

// ---------------- K0: transpose weights to bf16 [out][in] ----------------
__global__ void k_prep(const float* __restrict__ Wl, const float* __restrict__ Wr,
                       const float* __restrict__ Wg, const float* __restrict__ Wo,
                       s16* __restrict__ WlT, s16* __restrict__ WrT,
                       s16* __restrict__ WgT, s16* __restrict__ WoT) {
    const float* src;
    s16* dst;
    switch (blockIdx.x) {
        case 0: src = Wl; dst = WlT; break;
        case 1: src = Wr; dst = WrT; break;
        case 2: src = Wg; dst = WgT; break;
        default: src = Wo; dst = WoT; break;
    }
    for (int e = threadIdx.x; e < 128 * 128; e += blockDim.x) {
        int o = e >> 7, i = e & 127;
        dst[e] = f2bf(src[i * 128 + o]);  // WT[o][i] = W[i][o]
    }
}

// ---------------- K1: projection GEMM, output transposed [h][pos] ----------------
template <int COLMODE>
__global__ __launch_bounds__(256) void k_proj(const float* __restrict__ pair,
                                              const s16* __restrict__ WT,
                                              const float* __restrict__ bias,
                                              s16* __restrict__ outT) {
    __shared__ __align__(16) s16 As[128 * 128];  // 32KB, XOR-swizzled rows (256B)
    const int t = threadIdx.x;
    const int b = blockIdx.x;
    const int c0 = b & 511, rb = b >> 9;
    {
        const int p = t >> 1;
        const int dh = (t & 1) << 6;
        long gpos = COLMODE ? ((long)(rb * 128 + p) * 512 + c0) : ((long)b * 128 + p);
        const float* src = pair + gpos * 128 + dh;
        const int swz = (p & 7) << 4;
        char* lrow = (char*)As + p * 256;
#pragma unroll
        for (int g = 0; g < 8; ++g) {
            f32x4 v0 = *(const f32x4*)(src + g * 8);
            f32x4 v1 = *(const f32x4*)(src + g * 8 + 4);
            s16x8 pk;
            pk[0] = f2bf(v0[0]); pk[1] = f2bf(v0[1]); pk[2] = f2bf(v0[2]); pk[3] = f2bf(v0[3]);
            pk[4] = f2bf(v1[0]); pk[5] = f2bf(v1[1]); pk[6] = f2bf(v1[2]); pk[7] = f2bf(v1[3]);
            *(s16x8*)(lrow + ((dh * 2 + g * 16) ^ swz)) = pk;
        }
    }
    __syncthreads();
    const int w = t >> 6, l = t & 63;
    const int wr = (w >> 1) * 64, wc = (w & 1) * 64;
    const int lr = l & 15, lg = l >> 4;
    f32x4 acc[4][4];
#pragma unroll
    for (int mi = 0; mi < 4; ++mi)
#pragma unroll
        for (int ni = 0; ni < 4; ++ni) acc[mi][ni] = (f32x4){0.f, 0.f, 0.f, 0.f};
#pragma unroll
    for (int ks = 0; ks < 4; ++ks) {
        const int kk = ks * 32 + lg * 8;
        s16x8 af[4], bfv[4];
#pragma unroll
        for (int mi = 0; mi < 4; ++mi) {
            int row = wr + mi * 16 + lr;
            af[mi] = *(const s16x8*)((const char*)As + ((row * 256 + kk * 2) ^ ((row & 7) << 4)));
        }
#pragma unroll
        for (int ni = 0; ni < 4; ++ni) {
            int h = wc + ni * 16 + lr;
            bfv[ni] = *(const s16x8*)(WT + h * 128 + kk);
        }
#pragma unroll
        for (int mi = 0; mi < 4; ++mi)
#pragma unroll
            for (int ni = 0; ni < 4; ++ni)
                acc[mi][ni] = __builtin_amdgcn_mfma_f32_16x16x32_bf16(af[mi], bfv[ni], acc[mi][ni], 0, 0, 0);
    }
#pragma unroll
    for (int ni = 0; ni < 4; ++ni) {
        const int h = wc + ni * 16 + lr;
        const float bv = bias[h];
        long base = (long)h * NPOS + (COLMODE ? ((long)c0 * 512 + rb * 128) : ((long)b * 128));
#pragma unroll
        for (int mi = 0; mi < 4; ++mi) {
            const int prow = wr + mi * 16 + lg * 4;
            s16x4 pk;
#pragma unroll
            for (int r = 0; r < 4; ++r) pk[r] = f2bf(acc[mi][ni][r] + bv);
            *(s16x4*)(outT + base + prow) = pk;
        }
    }
}

// ---------------- K2: triangle einsum = 128 batched 512^3 GEMMs ----------------
__global__ __launch_bounds__(256) void k_tri(const s16* __restrict__ leftT,
                                             const s16* __restrict__ rightTT,
                                             s16* __restrict__ tri) {
    __shared__ __align__(16) s16 As[128 * 64];
    __shared__ __align__(16) s16 Bs[128 * 64];
    const int t = threadIdx.x;
    const int logical = ((blockIdx.x & 7) << 8) | (blockIdx.x >> 3);
    const int h = logical >> 4;
    const int ti = (logical >> 2) & 3, tj = logical & 3;
    const s16* Ap = leftT + (long)h * NPOS + ti * 128 * 512;
    const s16* Bp = rightTT + (long)h * NPOS + tj * 128 * 512;
    const int w = t >> 6, l = t & 63;
    const int wr = (w >> 1) * 64, wc = (w & 1) * 64;
    const int lr = l & 15, lg = l >> 4;
    const int srow = t >> 3;
    const int skk = (t & 7) << 3;
    f32x4 acc[4][4];
#pragma unroll
    for (int mi = 0; mi < 4; ++mi)
#pragma unroll
        for (int ni = 0; ni < 4; ++ni) acc[mi][ni] = (f32x4){0.f, 0.f, 0.f, 0.f};
    for (int kb = 0; kb < 512; kb += 64) {
        __syncthreads();
#pragma unroll
        for (int P = 0; P < 4; ++P) {
            int row = P * 32 + srow;
            int kks = skk ^ ((row & 7) << 3);
            unsigned loff = P * 4096 + w * 1024;
            gload_lds16(Ap + row * 512 + kb + kks, (char*)As + loff);
            gload_lds16(Bp + row * 512 + kb + kks, (char*)Bs + loff);
        }
        __syncthreads();
#pragma unroll
        for (int ks = 0; ks < 2; ++ks) {
            const int kk = ks * 32 + lg * 8;
            s16x8 af[4], bfv[4];
#pragma unroll
            for (int mi = 0; mi < 4; ++mi) {
                int row = wr + mi * 16 + lr;
                af[mi] = *(const s16x8*)((const char*)As + ((row * 128 + kk * 2) ^ ((row & 7) << 4)));
            }
#pragma unroll
            for (int ni = 0; ni < 4; ++ni) {
                int row = wc + ni * 16 + lr;
                bfv[ni] = *(const s16x8*)((const char*)Bs + ((row * 128 + kk * 2) ^ ((row & 7) << 4)));
            }
#pragma unroll
            for (int mi = 0; mi < 4; ++mi)
#pragma unroll
                for (int ni = 0; ni < 4; ++ni)
                    acc[mi][ni] = __builtin_amdgcn_mfma_f32_16x16x32_bf16(af[mi], bfv[ni], acc[mi][ni], 0, 0, 0);
        }
    }
#pragma unroll
    for (int mi = 0; mi < 4; ++mi) {
#pragma unroll
        for (int r = 0; r < 4; ++r) {
            int i = ti * 128 + wr + mi * 16 + lg * 4 + r;
            s16* dst = tri + (long)h * NPOS + (long)i * 512 + tj * 128 + wc;
#pragma unroll
            for (int ni = 0; ni < 4; ++ni) dst[ni * 16 + lr] = f2bf(acc[mi][ni][r]);
        }
    }
}

// ---------------- K2b: transpose tri[h][pos] -> triT[pos][h] ----------------
__global__ __launch_bounds__(256) void k_trT(const s16* __restrict__ tri,
                                             s16* __restrict__ triT) {
    __shared__ __align__(16) s16 Ts[128 * 256];  // 64KB, [h][pos] swizzled
    const int t = threadIdx.x;
    const int w = t >> 6;
    const long posBase = (long)blockIdx.x * 256;
#pragma unroll
    for (int P = 0; P < 16; ++P) {
        const int S = P * 256 + t;
        const int h = S >> 5, u = S & 31;
        const int ug = u ^ ((h >> 3) & 7);
        gload_lds16(tri + (long)h * NPOS + posBase + (ug << 3),
                    (char*)Ts + (P * 256 + w * 64) * 16);
    }
    __syncthreads();
    const int hc = t & 15;
    const int pr = t >> 4;
    const int g = hc & 7;
#pragma unroll
    for (int it = 0; it < 16; ++it) {
        const int p = pr + it * 16;
        const int pu = (p >> 3) ^ g, po = p & 7;
        s16x8 pk;
#pragma unroll
        for (int j = 0; j < 8; ++j)
            pk[j] = Ts[(hc * 8 + j) * 256 + pu * 8 + po];
        *(s16x8*)(triT + (posBase + p) * 128 + hc * 8) = pk;
    }
}

// ---------------- K3 v9: C^T form + async LDS staging (counted vmcnt) ----------------
// Meta-tile = 32 pos. Per meta per thread: 3 gload_lds16 (no VGPR dests -> MLP
// immune to the register scheduler). Double-buffered slots, XOR-swizzled on 16B
// units (pre-swizzled source + swizzled ds_read, involution u^=(row&7)).
// vmcnt waits are exact issue-order counts (in-order retirement, m135):
// per-iter N = 3,5,7,7,7,7,7,4. Prefetch for meta m+2 issued right after the
// post-GEMM barrier (slot m&1 is safe: all ds_reads drained by lgkmcnt(0)).
#define WAITVM(N) asm volatile("s_waitcnt vmcnt(" #N ")" ::: "memory")

#define SUBTILE(BUF, SUB) do {                                                        \
    const int row_ = (SUB) * 16 + lr;                                                 \
    const char* tbp_ = (const char*)&TRI[BUF][0] + row_ * 256;                        \
    const char* pbp_ = (const char*)&PA[BUF][0] + row_ * 512;                         \
    f32x4 accO_ = (f32x4){0.f, 0.f, 0.f, 0.f};                                        \
    f32x4 accG_ = (f32x4){0.f, 0.f, 0.f, 0.f};                                        \
    _Pragma("unroll")                                                                 \
    for (int ks = 0; ks < 4; ++ks) {                                                  \
        s16x8 tbv_ = *(const s16x8*)(tbp_ + ((((ks << 2) | lg) ^ rsw) << 4));         \
        f32x4 pa0_ = *(const f32x4*)(pbp_ + ((((ks << 3) | (lg << 1)) ^ rsw) << 4));  \
        f32x4 pa1_ = *(const f32x4*)(pbp_ + (((((ks << 3) | (lg << 1)) + 1) ^ rsw) << 4)); \
        s16x8 pf_;                                                                    \
        pf_[0] = f2bf(pa0_[0]); pf_[1] = f2bf(pa0_[1]);                               \
        pf_[2] = f2bf(pa0_[2]); pf_[3] = f2bf(pa0_[3]);                               \
        pf_[4] = f2bf(pa1_[0]); pf_[5] = f2bf(pa1_[1]);                               \
        pf_[6] = f2bf(pa1_[2]); pf_[7] = f2bf(pa1_[3]);                               \
        accO_ = __builtin_amdgcn_mfma_f32_16x16x32_bf16(wo[ks], tbv_, accO_, 0, 0, 0);\
        accG_ = __builtin_amdgcn_mfma_f32_16x16x32_bf16(wg[ks], pf_, accG_, 0, 0, 0); \
    }                                                                                 \
    f32x4 rs_ = *(const f32x4*)(pbp_ + ((((w << 2) | lg) ^ rsw) << 4));               \
    f32x4 xr_;                                                                        \
    _Pragma("unroll")                                                                 \
    for (int r = 0; r < 4; ++r) {                                                     \
        const float gate_ = 1.f / (1.f + __expf(-(accG_[r] + bg4[r])));               \
        xr_[r] = rs_[r] + gate_ * (accO_[r] + bo4[r]);                                \
    }                                                                                 \
    *(f32x4*)&xbuf[row_][dl] = xr_;                                                   \
} while (0)

#define LNPASS(P, META) do {                                                          \
    const int row_ = (P) * 16 + (t >> 5);                                             \
    f32x4 xv_ = *(const f32x4*)&xbuf[row_][lnc];                                      \
    float s_ = xv_[0] + xv_[1] + xv_[2] + xv_[3];                                     \
    s_ += __shfl_xor(s_, 1); s_ += __shfl_xor(s_, 2); s_ += __shfl_xor(s_, 4);        \
    s_ += __shfl_xor(s_, 8); s_ += __shfl_xor(s_, 16);                                \
    const float mu_ = s_ * 0.0078125f;                                                \
    float v_ = 0.f;                                                                   \
    _Pragma("unroll")                                                                 \
    for (int j = 0; j < 4; ++j) { float dd_ = xv_[j] - mu_; v_ += dd_ * dd_; }        \
    v_ += __shfl_xor(v_, 1); v_ += __shfl_xor(v_, 2); v_ += __shfl_xor(v_, 4);        \
    v_ += __shfl_xor(v_, 8); v_ += __shfl_xor(v_, 16);                                \
    const float rstd_ = rsqrtf(v_ * 0.0078125f + 1e-5f);                              \
    f32x4 o_;                                                                         \
    _Pragma("unroll")                                                                 \
    for (int j = 0; j < 4; ++j) o_[j] = (xv_[j] - mu_) * rstd_ * gm4[j] + bt4[j];     \
    *(f32x4*)(out + ((META) * 32 + row_) * 128 + lnc) = o_;                           \
} while (0)

#define ITER(M, NLIT, DOPF) do {                                                      \
    WAITVM(NLIT);                                                                     \
    __builtin_amdgcn_s_barrier();                                                     \
    SUBTILE((M) & 1, 0);                                                              \
    SUBTILE((M) & 1, 1);                                                              \
    asm volatile("s_waitcnt lgkmcnt(0)" ::: "memory");                                \
    __builtin_amdgcn_s_barrier();                                                     \
    __builtin_amdgcn_sched_barrier(0);                                                \
    if (DOPF) stage((M) & 1, meta0 + (M) + 2);                                        \
    LNPASS(0, meta0 + (M));                                                           \
    LNPASS(1, meta0 + (M));                                                           \
} while (0)

__global__ __launch_bounds__(512, 2) void k_final(const float* __restrict__ pair,
                                                  const s16* __restrict__ triT,
                                                  const s16* __restrict__ WgT,
                                                  const s16* __restrict__ WoT,
                                                  const float* __restrict__ bgv,
                                                  const float* __restrict__ bov,
                                                  const float* __restrict__ gam,
                                                  const float* __restrict__ bet,
                                                  float* __restrict__ out) {
    __shared__ __align__(16) s16 TRI[2][32 * 128];   // 2 x 8KB  (bf16 [pos][h], swizzled)
    __shared__ __align__(16) float PA[2][32 * 128];  // 2 x 16KB (fp32 [pos][d], swizzled)
    __shared__ __align__(16) float xbuf[32][132];    // 16.9KB
    const int t = threadIdx.x;
    const int w = t >> 6, l = t & 63;
    const int lr = l & 15, lg = l >> 4;
    const int d0 = w << 4;             // wave's d-stripe
    const int dl = d0 + (lg << 2);     // lane's d base (epilogue rows)
    const int rsw = lr & 7;            // read-side swizzle key (row&7; rows = s*16+lr)
    // weights: loaded ONCE, A-operand of both GEMMs (32 VGPRs)
    s16x8 wo[4], wg[4];
#pragma unroll
    for (int ks = 0; ks < 4; ++ks) {
        wo[ks] = *(const s16x8*)(WoT + (d0 + lr) * 128 + ks * 32 + lg * 8);
        wg[ks] = *(const s16x8*)(WgT + (d0 + lr) * 128 + ks * 32 + lg * 8);
    }
    const f32x4 bo4 = *(const f32x4*)(bov + dl);
    const f32x4 bg4 = *(const f32x4*)(bgv + dl);
    const int lnc = (t & 31) << 2;     // LN: d chunk (f32x4)
    const f32x4 gm4 = *(const f32x4*)(gam + lnc);
    const f32x4 bt4 = *(const f32x4*)(bet + lnc);
    const long meta0 = (long)blockIdx.x * 8;

    // stage one 32-pos meta: 3 gload_lds16 per thread, linear LDS dest
    // (wave-uniform base + lane*16), source pre-swizzled by u^=(row&7).
    auto stage = [&](int buf, long meta) {
        const long pb = meta * 32;
        {
            const int row = t >> 4, u = t & 15;  // triT: 16 units x 16B per row
            gload_lds16(triT + (pb + row) * 128 + ((u ^ (row & 7)) << 3),
                        (char*)&TRI[buf][0] + t * 16);
        }
        {
            const int row = t >> 5, u = t & 31;  // pair rows 0..15: 32 units x 16B
            gload_lds16(pair + (pb + row) * 128 + ((u ^ (row & 7)) << 2),
                        (char*)&PA[buf][0] + t * 16);
        }
        {
            const int row = 16 + (t >> 5), u = t & 31;  // pair rows 16..31
            gload_lds16(pair + (pb + row) * 128 + ((u ^ (row & 7)) << 2),
                        (char*)&PA[buf][0] + 8192 + t * 16);
        }
    };

    stage(0, meta0 + 0);
    stage(1, meta0 + 1);
    ITER(0, 3, 1);
    ITER(1, 5, 1);
    ITER(2, 7, 1);
    ITER(3, 7, 1);
    ITER(4, 7, 1);
    ITER(5, 7, 1);
    ITER(6, 7, 0);
    ITER(7, 4, 0);
}

extern "C" void kernel_launch(void* const* d_in, const int* in_sizes, int n_in,
                              void* d_out, int out_size, void* d_ws, size_t ws_size,
                              hipStream_t stream) {
    const float* pair = (const float*)d_in[0];
    const float* Wl   = (const float*)d_in[1];
    const float* bl   = (const float*)d_in[2];
    const float* Wr   = (const float*)d_in[3];
    const float* br   = (const float*)d_in[4];
    const float* Wo   = (const float*)d_in[5];
    const float* bo   = (const float*)d_in[6];
    const float* Wg   = (const float*)d_in[7];
    const float* bg   = (const float*)d_in[8];
    const float* gam  = (const float*)d_in[9];
    const float* bet  = (const float*)d_in[10];
    float* out = (float*)d_out;

    s16* WlT = (s16*)d_ws;
    s16* WrT = WlT + 128 * 128;
    s16* WgT = WrT + 128 * 128;
    s16* WoT = WgT + 128 * 128;
    s16* leftT   = WoT + 128 * 128;            // [128][NPOS]; becomes triT after k_tri
    s16* rightTT = leftT + (long)128 * NPOS;   // [128][NPOS]
    s16* tri     = rightTT + (long)128 * NPOS; // [128][NPOS]
    s16* triT    = leftT;                      // [NPOS][128]

    k_prep<<<4, 256, 0, stream>>>(Wl, Wr, Wg, Wo, WlT, WrT, WgT, WoT);
    k_proj<0><<<2048, 256, 0, stream>>>(pair, WlT, bl, leftT);
    k_proj<1><<<2048, 256, 0, stream>>>(pair, WrT, br, rightTT);
    k_tri<<<2048, 256, 0, stream>>>(leftT, rightTT, tri);
    k_trT<<<1024, 256, 0, stream>>>(tri, triT);
    k_final<<<1024, 512, 0, stream>>>(pair, triT, WgT, WoT, bg, bo, gam, bet, out);
}